// Round 12
// baseline (719.930 us; speedup 1.0000x reference)
//
#include <hip/hip_runtime.h>
#include <math.h>

// ---------------------------------------------------------------------------
// SNN forward: psp (K=100 alpha FIR) -> conv/pool/fc -> spike (refractory scan)
// All arithmetic mirrors the JAX reference's f32 association order.
// Round 12: REVERT round-11 scan/FIR wave split (regression: barrier already
// serializes scan; dropping wave-0 from FIR lost issue width).  Back to
// round-10 FIR_ITEMS8.  NEW: conv3 COG 8->4, conv4 COG 4->2 to fix wave
// starvation (2.25-4.5 waves/SIMD -> 4.5-9).  Math unchanged (bit-exact).
// ---------------------------------------------------------------------------

#define THETA 10.0f
#define RSTRIDE 204   // words per series row: 200 + pad4; 16B aligned

// HQ[i] = h[i-15] for 15<=i<=114 (h[k] = (k/10)*exp(1-k/10)), else 0. 144 entries.
// rk[i] = REF_KERNEL[i+1] = (-40*(i+1))*exp(1-(i+1)),  i=0..14
// wtN = transposed weights: wt[(ci*K*K + tap)*Co + co] = W[co][ci][tap]
__global__ void prep_kernel(const float* __restrict__ W1, const float* __restrict__ W2,
                            const float* __restrict__ W3, const float* __restrict__ W4,
                            float* HQ, float* rk,
                            float* wt1, float* wt2, float* wt3, float* wt4) {
    int i = blockIdx.x * 256 + threadIdx.x;
    if (i < 144) {
        int k = i - 15;
        float val = 0.0f;
        if (k >= 0 && k <= 99) {
            float tf = (float)k;
            float x = tf / 10.0f;
            val = x * (float)exp((double)(1.0f - x));   // same expr as prior rounds
        }
        HQ[i] = val;
    } else if (i < 160) {
        int j = i - 144;
        if (j < 15) {
            float t = (float)(j + 1);
            rk[j] = (-40.0f * t) * (float)exp((double)(1.0f - t));
        }
    } else if (i < 960) {            // W1: 16 x 50
        int j = i - 160, co = j / 50, tp = j % 50;
        wt1[tp * 16 + co] = W1[j];
    } else if (i < 5568) {           // W2: 32 x 144
        int j = i - 960, co = j / 144, tp = j % 144;
        wt2[tp * 32 + co] = W2[j];
    } else if (i < 24000) {          // W3: 64 x 288
        int j = i - 5568, co = j / 288, tp = j % 288;
        wt3[tp * 64 + co] = W3[j];
    } else if (i < 60864) {          // W4: 64 x 576
        int j = i - 24000, co = j / 576, tp = j % 576;
        wt4[tp * 64 + co] = W4[j];
    }
}

// 16-FMA inner step, order identical to round 1 (qw,qz,qy,qx; k ascending
// per accumulator).  hA = coeff base vector, hB = next vector.
#define FIR_STEP(A0, A1, A2, A3, qx, qy, qz, qw, hA, hB)  \
    A0 = fmaf(hA.x, qw, A0);                              \
    A1 = fmaf(hA.y, qw, A1);                              \
    A2 = fmaf(hA.z, qw, A2);                              \
    A3 = fmaf(hA.w, qw, A3);                              \
    A0 = fmaf(hA.y, qz, A0);                              \
    A1 = fmaf(hA.z, qz, A1);                              \
    A2 = fmaf(hA.w, qz, A2);                              \
    A3 = fmaf(hB.x, qz, A3);                              \
    A0 = fmaf(hA.z, qy, A0);                              \
    A1 = fmaf(hA.w, qy, A1);                              \
    A2 = fmaf(hB.x, qy, A2);                              \
    A3 = fmaf(hB.y, qy, A3);                              \
    A0 = fmaf(hA.w, qx, A0);                              \
    A1 = fmaf(hB.x, qx, A1);                              \
    A2 = fmaf(hB.y, qx, A2);                              \
    A3 = fmaf(hB.z, qx, A3);

// 4 sequential scan steps on a float4 (ascending t), identical math.
#define SCAN4(XV, p, rk)                                          \
    {                                                             \
        float u_, sv_;                                            \
        u_ = XV.x + p[0]; sv_ = (u_ >= THETA) ? 1.0f : 0.0f;      \
        XV.x = sv_;                                               \
        _Pragma("unroll")                                         \
        for (int i_ = 0; i_ < 14; ++i_) p[i_] = fmaf(sv_, rk[i_], p[i_ + 1]); \
        p[14] = sv_ * rk[14];                                     \
        u_ = XV.y + p[0]; sv_ = (u_ >= THETA) ? 1.0f : 0.0f;      \
        XV.y = sv_;                                               \
        _Pragma("unroll")                                         \
        for (int i_ = 0; i_ < 14; ++i_) p[i_] = fmaf(sv_, rk[i_], p[i_ + 1]); \
        p[14] = sv_ * rk[14];                                     \
        u_ = XV.z + p[0]; sv_ = (u_ >= THETA) ? 1.0f : 0.0f;      \
        XV.z = sv_;                                               \
        _Pragma("unroll")                                         \
        for (int i_ = 0; i_ < 14; ++i_) p[i_] = fmaf(sv_, rk[i_], p[i_ + 1]); \
        p[14] = sv_ * rk[14];                                     \
        u_ = XV.w + p[0]; sv_ = (u_ >= THETA) ? 1.0f : 0.0f;      \
        XV.w = sv_;                                               \
        _Pragma("unroll")                                         \
        for (int i_ = 0; i_ < 14; ++i_) p[i_] = fmaf(sv_, rk[i_], p[i_ + 1]); \
        p[14] = sv_ * rk[14];                                     \
    }

// ---------------------------------------------------------------------------
// FIR item (8 outputs at t0=8*id): per j one b128 tile read + 32 FMA.
// Window: A=HQ4[j+2], B=HQ4[j+3], C=HQ4[j+4]; d=0 uses (A,B), d=1 uses (B,C).
// Out-of-range taps hit HQ zeros -> exact no-ops (all operands >= +0).
// ---------------------------------------------------------------------------
__device__ __forceinline__ void fir_run2(const float* __restrict__ row,
                                         const float4* __restrict__ HQ4,
                                         int t0, int jend, float4 (&acc)[2]) {
    float4 A = HQ4[2], B = HQ4[3], C = HQ4[4];
    const float* bp = row + t0 + 4;
    for (int j = 0; j <= jend; ++j) {
        const float4 qv = *reinterpret_cast<const float4*>(bp);
        const float4 N = HQ4[j + 5];
        FIR_STEP(acc[0].x, acc[0].y, acc[0].z, acc[0].w,
                 qv.x, qv.y, qv.z, qv.w, A, B)
        FIR_STEP(acc[1].x, acc[1].y, acc[1].z, acc[1].w,
                 qv.x, qv.y, qv.z, qv.w, B, C)
        A = B; B = C; C = N;
        bp -= 4;
    }
}

// Balanced wave->item table (item id i costs min(2i,25)+2 j-iters; wave sums
// 60..71 vs avg 63.3).  -1 = no item.  [round-10 table — R11's 7-wave split
// regressed: the post-scan barrier serializes scan for ALL waves anyway]
__device__ static const signed char FIR_ITEMS8[8][4] = {
    {24, 12, 8, -1}, {22, 21, 4, -1}, {20, 19, 3, -1}, {18, 17, 2, -1},
    {16, 15, 1, 0},  {13, 11, 5, -1}, {14, 10, 6, -1}, {23, 9, 7, -1}};

// ---------------------------------------------------------------------------
// Fused [spike ->] psp.  Block = 64 series x 8 waves, LDS tile [64][204].
// ---------------------------------------------------------------------------
template <bool SCAN>
__global__ __launch_bounds__(512) void spikepsp_kernel(const float* __restrict__ in,
                                                       float* __restrict__ out,
                                                       const float* __restrict__ HQ,
                                                       const float* __restrict__ rkt,
                                                       int n) {
    __shared__ __align__(16) float tile[64 * RSTRIDE];
    const int l = threadIdx.x & 63;
    const int w = threadIdx.x >> 6;
    const int s0 = blockIdx.x * 64;
    for (int i = threadIdx.x; i < 3200; i += 512) {
        const int slot = i / 50, q = i - slot * 50;
        const int ser = s0 + slot;
        float4 v = make_float4(0.f, 0.f, 0.f, 0.f);
        if (ser < n) v = *reinterpret_cast<const float4*>(in + (long)ser * 200 + 4 * q);
        *reinterpret_cast<float4*>(&tile[slot * RSTRIDE + 4 * q]) = v;
    }
    __syncthreads();
    if (SCAN) {
        if (w == 0) {
            float rk[15];
            #pragma unroll
            for (int i = 0; i < 15; ++i) rk[i] = rkt[i];
            float p[15];
            #pragma unroll
            for (int i = 0; i < 15; ++i) p[i] = 0.0f;
            float* row = tile + l * RSTRIDE;
            for (int tq = 0; tq < 50; ++tq) {
                float4 xv = *reinterpret_cast<const float4*>(&row[4 * tq]);
                SCAN4(xv, p, rk)
                *reinterpret_cast<float4*>(&row[4 * tq]) = xv;
            }
        }
        __syncthreads();
    }
    const bool valid = (s0 + l) < n;
    const float* row = tile + l * RSTRIDE;
    const float4* HQ4 = reinterpret_cast<const float4*>(HQ);
    float* op = out + (long)(s0 + l) * 200;
    #pragma unroll
    for (int k = 0; k < 4; ++k) {
        const int id = FIR_ITEMS8[w][k];
        if (id < 0) break;
        const int t0 = 8 * id;
        const int jend = ((2 * id < 25) ? 2 * id : 25) + 1;
        float4 acc[2];
        acc[0] = make_float4(0.f, 0.f, 0.f, 0.f);
        acc[1] = make_float4(0.f, 0.f, 0.f, 0.f);
        fir_run2(row, HQ4, t0, jend, acc);
        if (valid) {
            *reinterpret_cast<float4*>(op + t0) = acc[0];
            *reinterpret_cast<float4*>(op + t0 + 4) = acc[1];
        }
    }
}

// ---------------------------------------------------------------------------
// Fused spike -> psp -> 2x2 sum-pool (*11).  Block = 16 outputs = 64 input
// series (slot = 4*oi + pixel), 8 waves.  Pool combine = in-order quad
// shuffle sum ((p0+p1)+p2)+p3 then *11 — bit-identical to unfused.
// ---------------------------------------------------------------------------
__global__ __launch_bounds__(512) void spikepsppool_kernel(const float* __restrict__ in,
                                                           float* __restrict__ out,
                                                           const float* __restrict__ HQ,
                                                           const float* __restrict__ rkt,
                                                           int C, int HO, int WO) {
    __shared__ __align__(16) float tile[64 * RSTRIDE];
    __shared__ int sbase[64];
    const int l = threadIdx.x & 63;
    const int w = threadIdx.x >> 6;
    const int o0 = blockIdx.x * 16;
    const int H = 2 * HO, W = 2 * WO;
    if (threadIdx.x < 64) {
        const int oi = threadIdx.x >> 2, p = threadIdx.x & 3;
        const int o = o0 + oi;
        const int wo = o % WO; int tmp = o / WO;
        const int ho = tmp % HO; tmp /= HO;
        const int c = tmp % C; const int b = tmp / C;
        sbase[threadIdx.x] = ((b * C + c) * H + 2 * ho + (p >> 1)) * W + 2 * wo + (p & 1);
    }
    __syncthreads();
    for (int i = threadIdx.x; i < 3200; i += 512) {
        const int slot = i / 50, q = i - slot * 50;
        const float4 v = *reinterpret_cast<const float4*>(in + (long)sbase[slot] * 200 + 4 * q);
        *reinterpret_cast<float4*>(&tile[slot * RSTRIDE + 4 * q]) = v;
    }
    __syncthreads();
    if (w == 0) {
        float rk[15];
        #pragma unroll
        for (int i = 0; i < 15; ++i) rk[i] = rkt[i];
        float p[15];
        #pragma unroll
        for (int i = 0; i < 15; ++i) p[i] = 0.0f;
        float* row = tile + l * RSTRIDE;
        for (int tq = 0; tq < 50; ++tq) {
            float4 xv = *reinterpret_cast<const float4*>(&row[4 * tq]);
            SCAN4(xv, p, rk)
            *reinterpret_cast<float4*>(&row[4 * tq]) = xv;
        }
    }
    __syncthreads();
    const int qb = l & ~3;
    const float* row = tile + l * RSTRIDE;
    const float4* HQ4 = reinterpret_cast<const float4*>(HQ);
    float* op = out + (long)(o0 + (l >> 2)) * 200;
    auto qsum = [&](float v) -> float {
        const float v0 = __shfl(v, qb + 0);
        const float v1 = __shfl(v, qb + 1);
        const float v2 = __shfl(v, qb + 2);
        const float v3 = __shfl(v, qb + 3);
        return (((v0 + v1) + v2) + v3) * 11.0f;
    };
    #pragma unroll
    for (int k = 0; k < 4; ++k) {
        const int id = FIR_ITEMS8[w][k];
        if (id < 0) break;
        const int t0 = 8 * id;
        const int jend = ((2 * id < 25) ? 2 * id : 25) + 1;
        float4 acc[2];
        acc[0] = make_float4(0.f, 0.f, 0.f, 0.f);
        acc[1] = make_float4(0.f, 0.f, 0.f, 0.f);
        fir_run2(row, HQ4, t0, jend, acc);
        #pragma unroll
        for (int d = 0; d < 2; ++d) {
            float4 r;
            r.x = qsum(acc[d].x); r.y = qsum(acc[d].y);
            r.z = qsum(acc[d].z); r.w = qsum(acc[d].w);
            if ((l & 3) == 0)
                *reinterpret_cast<float4*>(op + t0 + 4 * d) = r;
        }
    }
}

// ---------------------------------------------------------------------------
// conv1 (K=5): float4-of-t, transposed weights, 16 co accumulators.
// ---------------------------------------------------------------------------
template <int K, int PAD, int CI, int COG>
__global__ __launch_bounds__(256) void conv_kernel(const float* __restrict__ x,
                                                   const float* __restrict__ wt,
                                                   float* __restrict__ out,
                                                   int Co, int H, int W,
                                                   int HO, int WO) {
    const int l = threadIdx.x & 63;
    const int wv = threadIdx.x >> 6;
    if (l >= 50) return;
    const int p = blockIdx.x * 4 + wv;
    const int wo = p % WO, ho = p / WO;
    const int co0 = blockIdx.y * COG;
    const int b = blockIdx.z;
    const int t0 = l * 4;
    float4 acc[COG];
    #pragma unroll
    for (int c = 0; c < COG; ++c) acc[c] = make_float4(0.f, 0.f, 0.f, 0.f);
    const float* xb = x + ((long)b * CI * H * W) * 200 + t0;
    for (int ci = 0; ci < CI; ++ci) {
        #pragma unroll
        for (int kh = 0; kh < K; ++kh) {
            const int hi = ho + kh - PAD;
            if (hi < 0 || hi >= H) continue;
            #pragma unroll
            for (int kw = 0; kw < K; ++kw) {
                const int wi = wo + kw - PAD;
                if (wi < 0 || wi >= W) continue;
                const float4 v = *reinterpret_cast<const float4*>(
                    xb + ((long)(ci * H + hi) * W + wi) * 200);
                const float* wp = wt + ((ci * K + kh) * K + kw) * Co + co0;
                #pragma unroll
                for (int c = 0; c < COG; ++c) {
                    const float wv_ = wp[c];
                    acc[c].x = fmaf(wv_, v.x, acc[c].x);
                    acc[c].y = fmaf(wv_, v.y, acc[c].y);
                    acc[c].z = fmaf(wv_, v.z, acc[c].z);
                    acc[c].w = fmaf(wv_, v.w, acc[c].w);
                }
            }
        }
    }
    const long hwN = (long)HO * WO;
    const long ob = ((long)(b * Co + co0) * HO + ho) * WO + wo;
    #pragma unroll
    for (int c = 0; c < COG; ++c)
        *reinterpret_cast<float4*>(out + (ob + c * hwN) * 200 + t0) = acc[c];
}

// ---------------------------------------------------------------------------
// K=3 convs: ci-software-pipelined, zero-filled OOB taps (bit-exact).
// ---------------------------------------------------------------------------
template <int CI, int COG>
__global__ __launch_bounds__(256) void conv3_kernel(const float* __restrict__ x,
                                                    const float* __restrict__ wt,
                                                    float* __restrict__ out,
                                                    int Co, int H, int W) {
    const int l = threadIdx.x & 63;
    const int wv = threadIdx.x >> 6;
    if (l >= 50) return;
    const int p = blockIdx.x * 4 + wv;
    const int wo = p % W, ho = p / W;
    const int co0 = blockIdx.y * COG;
    const int b = blockIdx.z;
    const int t0 = l * 4;
    float4 acc[COG];
    #pragma unroll
    for (int c = 0; c < COG; ++c) acc[c] = make_float4(0.f, 0.f, 0.f, 0.f);

    bool vm[9];
    #pragma unroll
    for (int i = 0; i < 9; ++i) {
        const int hi = ho + i / 3 - 1, wi = wo + i % 3 - 1;
        vm[i] = (hi >= 0) && (hi < H) && (wi >= 0) && (wi < W);
    }
    const long cis = (long)H * W * 200;
    const float* pb = x + (long)b * CI * cis + ((long)(ho - 1) * W + (wo - 1)) * 200 + t0;

    float4 bufA[9], bufB[9];
    auto ld = [&](int ci, float4 (&B)[9]) {
        const float* pc = pb + ci * cis;
        #pragma unroll
        for (int i = 0; i < 9; ++i) {
            B[i] = vm[i] ? *reinterpret_cast<const float4*>(pc + ((i / 3) * W + (i % 3)) * 200)
                         : make_float4(0.f, 0.f, 0.f, 0.f);
        }
    };
    auto fm = [&](const float4 (&B)[9], int ci) {
        #pragma unroll
        for (int i = 0; i < 9; ++i) {
            const float* wp = wt + (ci * 9 + i) * Co + co0;
            #pragma unroll
            for (int c = 0; c < COG; ++c) {
                const float wv_ = wp[c];
                acc[c].x = fmaf(wv_, B[i].x, acc[c].x);
                acc[c].y = fmaf(wv_, B[i].y, acc[c].y);
                acc[c].z = fmaf(wv_, B[i].z, acc[c].z);
                acc[c].w = fmaf(wv_, B[i].w, acc[c].w);
            }
        }
    };

    ld(0, bufA);
    #pragma unroll 1
    for (int ci = 0; ci < CI; ci += 2) {
        ld(ci + 1, bufB);
        fm(bufA, ci);
        if (ci + 2 < CI) ld(ci + 2, bufA);
        fm(bufB, ci + 1);
    }

    const long hwN = (long)H * W;
    const long ob = ((long)(b * Co + co0) * H + ho) * W + wo;
    #pragma unroll
    for (int c = 0; c < COG; ++c)
        *reinterpret_cast<float4*>(out + (ob + c * hwN) * 200 + t0) = acc[c];
}

// ---------------------------------------------------------------------------
// Standalone spike scan (only the tiny final fc->spike uses this now).
// ---------------------------------------------------------------------------
__global__ __launch_bounds__(256) void spike_kernel(const float* __restrict__ v,
                                                    float* __restrict__ s,
                                                    const float* __restrict__ rkt,
                                                    int n) {
    const int nid = blockIdx.x * 256 + threadIdx.x;
    if (nid >= n) return;
    float rk[15];
    #pragma unroll
    for (int i = 0; i < 15; ++i) rk[i] = rkt[i];
    float p[15];
    #pragma unroll
    for (int i = 0; i < 15; ++i) p[i] = 0.0f;
    const float* vp = v + (long)nid * 200;
    float* sp = s + (long)nid * 200;
    for (int t = 0; t < 200; ++t) {
        const float u = vp[t] + p[0];
        const float sv = (u >= THETA) ? 1.0f : 0.0f;
        sp[t] = sv;
        #pragma unroll
        for (int i = 0; i < 14; ++i) p[i] = fmaf(sv, rk[i], p[i + 1]);
        p[14] = sv * rk[14];
    }
}

// ---------------------------------------------------------------------------
// FC: out[b,k,t] = sum_m x[b,m,t] * Wfc[k,m], m ascending (2304) — chain
// order unchanged (bit-exact).  LDS t-major xs[q][2308]; 80 active lanes.
// ---------------------------------------------------------------------------
__global__ __launch_bounds__(128) void fc_kernel(const float* __restrict__ x,
                                                 const float* __restrict__ wf,
                                                 float* __restrict__ out) {
    __shared__ __align__(16) float xs[8 * 2308];
    const int b = blockIdx.x;          // 4
    const int t0 = blockIdx.y * 8;     // 25 chunks
    const int tid = threadIdx.x;
    const float* xb = x + (long)b * 2304 * 200 + t0;
    for (int i = tid; i < 4608; i += 128) {
        const int m = i >> 1, qh = (i & 1) * 4;
        const float4 v = *reinterpret_cast<const float4*>(xb + (long)m * 200 + qh);
        xs[(qh + 0) * 2308 + m] = v.x;
        xs[(qh + 1) * 2308 + m] = v.y;
        xs[(qh + 2) * 2308 + m] = v.z;
        xs[(qh + 3) * 2308 + m] = v.w;
    }
    __syncthreads();
    if (tid < 80) {
        const int k = tid >> 3, q = tid & 7;
        float a = 0.0f;
        const float* wp = wf + k * 2304;
        const float* xp = xs + q * 2308;
        for (int m4 = 0; m4 < 2304; m4 += 4) {
            const float4 xv = *reinterpret_cast<const float4*>(xp + m4);
            const float4 wv = *reinterpret_cast<const float4*>(wp + m4);
            a = fmaf(wv.x, xv.x, a);
            a = fmaf(wv.y, xv.y, a);
            a = fmaf(wv.z, xv.z, a);
            a = fmaf(wv.w, xv.w, a);
        }
        out[((long)b * 10 + k) * 200 + t0 + q] = a;
    }
}

extern "C" void kernel_launch(void* const* d_in, const int* in_sizes, int n_in,
                              void* d_out, int out_size, void* d_ws, size_t ws_size,
                              hipStream_t stream) {
    const float* x_in = (const float*)d_in[0];  // (4,2,50,50,200)
    const float* W1 = (const float*)d_in[1];    // (16,2,5,5)
    const float* W2 = (const float*)d_in[2];    // (32,16,3,3)
    const float* W3 = (const float*)d_in[3];    // (64,32,3,3)
    const float* W4 = (const float*)d_in[4];    // (64,64,3,3)
    const float* Wfc = (const float*)d_in[5];   // (10,64,6,6)
    float* outp = (float*)d_out;                // (4,10,200)

    float* ws = (float*)d_ws;
    float* HQ  = ws;                  // 144 (16B aligned)
    float* rk  = ws + 144;            // 15 (+1 pad)
    float* wt1 = ws + 160;            // 800
    float* wt2 = wt1 + 800;           // 4608
    float* wt3 = wt2 + 4608;          // 18432
    float* wt4 = wt3 + 18432;         // 36864
    float* A   = wt4 + 36864;         // 7,372,800
    float* B   = A + 7372800;         // 29,491,200
    float* C   = B + 29491200;        // 14,745,600

    hipLaunchKernelGGL(prep_kernel, dim3(238), dim3(256), 0, stream,
                       W1, W2, W3, W4, HQ, rk, wt1, wt2, wt3, wt4);

    // p0 = psp(input): 20000 series (no scan)
    hipLaunchKernelGGL((spikepsp_kernel<false>), dim3(313), dim3(512), 0, stream,
                       x_in, A, HQ, rk, 20000);
    // c1 = conv1(p0): (4,16,48,48,200)
    hipLaunchKernelGGL((conv_kernel<5, 1, 2, 16>), dim3(2304 / 4, 1, 4), dim3(256), 0, stream,
                       A, wt1, B, 16, 50, 50, 48, 48);
    // o1 = pool(psp(spike(c1))): 36864 outputs
    hipLaunchKernelGGL(spikepsppool_kernel, dim3(36864 / 16), dim3(512), 0, stream,
                       B, A, HQ, rk, 16, 24, 24);
    // p2 = psp(spike(o1)): 36864 series
    hipLaunchKernelGGL((spikepsp_kernel<true>), dim3(36864 / 64), dim3(512), 0, stream,
                       A, B, HQ, rk, 36864);
    // c2 = conv2(p2): (4,32,24,24,200)
    hipLaunchKernelGGL((conv3_kernel<16, 8>), dim3(576 / 4, 4, 4), dim3(256), 0, stream,
                       B, wt2, C, 32, 24, 24);
    // o2 = pool(psp(spike(c2))): 18432 outputs
    hipLaunchKernelGGL(spikepsppool_kernel, dim3(18432 / 16), dim3(512), 0, stream,
                       C, A, HQ, rk, 32, 12, 12);
    // p4 = psp(spike(o2)): 18432 series
    hipLaunchKernelGGL((spikepsp_kernel<true>), dim3(18432 / 64), dim3(512), 0, stream,
                       A, B, HQ, rk, 18432);
    // c3 = conv3(p4): (4,64,12,12,200)  [COG=4: 9216 waves = 9/SIMD]
    hipLaunchKernelGGL((conv3_kernel<32, 4>), dim3(144 / 4, 16, 4), dim3(256), 0, stream,
                       B, wt3, C, 64, 12, 12);
    // o3 = pool(psp(spike(c3))): 9216 outputs
    hipLaunchKernelGGL(spikepsppool_kernel, dim3(9216 / 16), dim3(512), 0, stream,
                       C, A, HQ, rk, 64, 6, 6);
    // p6 = psp(spike(o3)): 9216 series
    hipLaunchKernelGGL((spikepsp_kernel<true>), dim3(9216 / 64), dim3(512), 0, stream,
                       A, B, HQ, rk, 9216);
    // c4 = conv4(p6): (4,64,6,6,200)  [COG=2: 4608 waves = 4.5/SIMD]
    hipLaunchKernelGGL((conv3_kernel<64, 2>), dim3(36 / 4, 32, 4), dim3(256), 0, stream,
                       B, wt4, C, 64, 6, 6);
    // p7 = psp(spike(c4)): 9216 series
    hipLaunchKernelGGL((spikepsp_kernel<true>), dim3(9216 / 64), dim3(512), 0, stream,
                       C, B, HQ, rk, 9216);
    // fc: (4,10,200) — block per (b, 8-t chunk), 128 threads
    hipLaunchKernelGGL(fc_kernel, dim3(4, 25), dim3(128), 0, stream, B, Wfc, A);
    // final spike -> d_out: 40 series
    hipLaunchKernelGGL(spike_kernel, dim3(1), dim3(256), 0, stream, A, outp, rk, 40);
    (void)in_sizes; (void)n_in; (void)out_size; (void)ws_size;
}

// Round 13
// 675.054 us; speedup vs baseline: 1.0665x; 1.0665x over previous
//
#include <hip/hip_runtime.h>
#include <math.h>

// ---------------------------------------------------------------------------
// SNN forward: psp (K=100 alpha FIR) -> conv/pool/fc -> spike (refractory scan)
// All arithmetic mirrors the JAX reference's f32 association order.
// Round 13: exact revert to round-10 configuration (best: 674.8 us) —
// conv3 COG=8 / conv4 COG=4 (round-12 COG cut caused 5x HBM re-fetch),
// FIR on all 8 waves (round-11 scan-split lost issue width).  One safe
// tweak: fc staging widened to 256 threads.  Math unchanged (bit-exact).
// ---------------------------------------------------------------------------

#define THETA 10.0f
#define RSTRIDE 204   // words per series row: 200 + pad4; 16B aligned

// HQ[i] = h[i-15] for 15<=i<=114 (h[k] = (k/10)*exp(1-k/10)), else 0. 144 entries.
// rk[i] = REF_KERNEL[i+1] = (-40*(i+1))*exp(1-(i+1)),  i=0..14
// wtN = transposed weights: wt[(ci*K*K + tap)*Co + co] = W[co][ci][tap]
__global__ void prep_kernel(const float* __restrict__ W1, const float* __restrict__ W2,
                            const float* __restrict__ W3, const float* __restrict__ W4,
                            float* HQ, float* rk,
                            float* wt1, float* wt2, float* wt3, float* wt4) {
    int i = blockIdx.x * 256 + threadIdx.x;
    if (i < 144) {
        int k = i - 15;
        float val = 0.0f;
        if (k >= 0 && k <= 99) {
            float tf = (float)k;
            float x = tf / 10.0f;
            val = x * (float)exp((double)(1.0f - x));   // same expr as prior rounds
        }
        HQ[i] = val;
    } else if (i < 160) {
        int j = i - 144;
        if (j < 15) {
            float t = (float)(j + 1);
            rk[j] = (-40.0f * t) * (float)exp((double)(1.0f - t));
        }
    } else if (i < 960) {            // W1: 16 x 50
        int j = i - 160, co = j / 50, tp = j % 50;
        wt1[tp * 16 + co] = W1[j];
    } else if (i < 5568) {           // W2: 32 x 144
        int j = i - 960, co = j / 144, tp = j % 144;
        wt2[tp * 32 + co] = W2[j];
    } else if (i < 24000) {          // W3: 64 x 288
        int j = i - 5568, co = j / 288, tp = j % 288;
        wt3[tp * 64 + co] = W3[j];
    } else if (i < 60864) {          // W4: 64 x 576
        int j = i - 24000, co = j / 576, tp = j % 576;
        wt4[tp * 64 + co] = W4[j];
    }
}

// 16-FMA inner step, order identical to round 1 (qw,qz,qy,qx; k ascending
// per accumulator).  hA = coeff base vector, hB = next vector.
#define FIR_STEP(A0, A1, A2, A3, qx, qy, qz, qw, hA, hB)  \
    A0 = fmaf(hA.x, qw, A0);                              \
    A1 = fmaf(hA.y, qw, A1);                              \
    A2 = fmaf(hA.z, qw, A2);                              \
    A3 = fmaf(hA.w, qw, A3);                              \
    A0 = fmaf(hA.y, qz, A0);                              \
    A1 = fmaf(hA.z, qz, A1);                              \
    A2 = fmaf(hA.w, qz, A2);                              \
    A3 = fmaf(hB.x, qz, A3);                              \
    A0 = fmaf(hA.z, qy, A0);                              \
    A1 = fmaf(hA.w, qy, A1);                              \
    A2 = fmaf(hB.x, qy, A2);                              \
    A3 = fmaf(hB.y, qy, A3);                              \
    A0 = fmaf(hA.w, qx, A0);                              \
    A1 = fmaf(hB.x, qx, A1);                              \
    A2 = fmaf(hB.y, qx, A2);                              \
    A3 = fmaf(hB.z, qx, A3);

// 4 sequential scan steps on a float4 (ascending t), identical math.
#define SCAN4(XV, p, rk)                                          \
    {                                                             \
        float u_, sv_;                                            \
        u_ = XV.x + p[0]; sv_ = (u_ >= THETA) ? 1.0f : 0.0f;      \
        XV.x = sv_;                                               \
        _Pragma("unroll")                                         \
        for (int i_ = 0; i_ < 14; ++i_) p[i_] = fmaf(sv_, rk[i_], p[i_ + 1]); \
        p[14] = sv_ * rk[14];                                     \
        u_ = XV.y + p[0]; sv_ = (u_ >= THETA) ? 1.0f : 0.0f;      \
        XV.y = sv_;                                               \
        _Pragma("unroll")                                         \
        for (int i_ = 0; i_ < 14; ++i_) p[i_] = fmaf(sv_, rk[i_], p[i_ + 1]); \
        p[14] = sv_ * rk[14];                                     \
        u_ = XV.z + p[0]; sv_ = (u_ >= THETA) ? 1.0f : 0.0f;      \
        XV.z = sv_;                                               \
        _Pragma("unroll")                                         \
        for (int i_ = 0; i_ < 14; ++i_) p[i_] = fmaf(sv_, rk[i_], p[i_ + 1]); \
        p[14] = sv_ * rk[14];                                     \
        u_ = XV.w + p[0]; sv_ = (u_ >= THETA) ? 1.0f : 0.0f;      \
        XV.w = sv_;                                               \
        _Pragma("unroll")                                         \
        for (int i_ = 0; i_ < 14; ++i_) p[i_] = fmaf(sv_, rk[i_], p[i_ + 1]); \
        p[14] = sv_ * rk[14];                                     \
    }

// ---------------------------------------------------------------------------
// FIR item (8 outputs at t0=8*id): per j one b128 tile read + 32 FMA.
// Window: A=HQ4[j+2], B=HQ4[j+3], C=HQ4[j+4]; d=0 uses (A,B), d=1 uses (B,C).
// Out-of-range taps hit HQ zeros -> exact no-ops (all operands >= +0).
// ---------------------------------------------------------------------------
__device__ __forceinline__ void fir_run2(const float* __restrict__ row,
                                         const float4* __restrict__ HQ4,
                                         int t0, int jend, float4 (&acc)[2]) {
    float4 A = HQ4[2], B = HQ4[3], C = HQ4[4];
    const float* bp = row + t0 + 4;
    for (int j = 0; j <= jend; ++j) {
        const float4 qv = *reinterpret_cast<const float4*>(bp);
        const float4 N = HQ4[j + 5];
        FIR_STEP(acc[0].x, acc[0].y, acc[0].z, acc[0].w,
                 qv.x, qv.y, qv.z, qv.w, A, B)
        FIR_STEP(acc[1].x, acc[1].y, acc[1].z, acc[1].w,
                 qv.x, qv.y, qv.z, qv.w, B, C)
        A = B; B = C; C = N;
        bp -= 4;
    }
}

// Balanced wave->item table (item id i costs min(2i,25)+2 j-iters; wave sums
// 60..71 vs avg 63.3).  -1 = no item.
__device__ static const signed char FIR_ITEMS8[8][4] = {
    {24, 12, 8, -1}, {22, 21, 4, -1}, {20, 19, 3, -1}, {18, 17, 2, -1},
    {16, 15, 1, 0},  {13, 11, 5, -1}, {14, 10, 6, -1}, {23, 9, 7, -1}};

// ---------------------------------------------------------------------------
// Fused [spike ->] psp.  Block = 64 series x 8 waves, LDS tile [64][204].
// ---------------------------------------------------------------------------
template <bool SCAN>
__global__ __launch_bounds__(512) void spikepsp_kernel(const float* __restrict__ in,
                                                       float* __restrict__ out,
                                                       const float* __restrict__ HQ,
                                                       const float* __restrict__ rkt,
                                                       int n) {
    __shared__ __align__(16) float tile[64 * RSTRIDE];
    const int l = threadIdx.x & 63;
    const int w = threadIdx.x >> 6;
    const int s0 = blockIdx.x * 64;
    for (int i = threadIdx.x; i < 3200; i += 512) {
        const int slot = i / 50, q = i - slot * 50;
        const int ser = s0 + slot;
        float4 v = make_float4(0.f, 0.f, 0.f, 0.f);
        if (ser < n) v = *reinterpret_cast<const float4*>(in + (long)ser * 200 + 4 * q);
        *reinterpret_cast<float4*>(&tile[slot * RSTRIDE + 4 * q]) = v;
    }
    __syncthreads();
    if (SCAN) {
        if (w == 0) {
            float rk[15];
            #pragma unroll
            for (int i = 0; i < 15; ++i) rk[i] = rkt[i];
            float p[15];
            #pragma unroll
            for (int i = 0; i < 15; ++i) p[i] = 0.0f;
            float* row = tile + l * RSTRIDE;
            for (int tq = 0; tq < 50; ++tq) {
                float4 xv = *reinterpret_cast<const float4*>(&row[4 * tq]);
                SCAN4(xv, p, rk)
                *reinterpret_cast<float4*>(&row[4 * tq]) = xv;
            }
        }
        __syncthreads();
    }
    const bool valid = (s0 + l) < n;
    const float* row = tile + l * RSTRIDE;
    const float4* HQ4 = reinterpret_cast<const float4*>(HQ);
    float* op = out + (long)(s0 + l) * 200;
    #pragma unroll
    for (int k = 0; k < 4; ++k) {
        const int id = FIR_ITEMS8[w][k];
        if (id < 0) break;
        const int t0 = 8 * id;
        const int jend = ((2 * id < 25) ? 2 * id : 25) + 1;
        float4 acc[2];
        acc[0] = make_float4(0.f, 0.f, 0.f, 0.f);
        acc[1] = make_float4(0.f, 0.f, 0.f, 0.f);
        fir_run2(row, HQ4, t0, jend, acc);
        if (valid) {
            *reinterpret_cast<float4*>(op + t0) = acc[0];
            *reinterpret_cast<float4*>(op + t0 + 4) = acc[1];
        }
    }
}

// ---------------------------------------------------------------------------
// Fused spike -> psp -> 2x2 sum-pool (*11).  Block = 16 outputs = 64 input
// series (slot = 4*oi + pixel), 8 waves.  Pool combine = in-order quad
// shuffle sum ((p0+p1)+p2)+p3 then *11 — bit-identical to unfused.
// ---------------------------------------------------------------------------
__global__ __launch_bounds__(512) void spikepsppool_kernel(const float* __restrict__ in,
                                                           float* __restrict__ out,
                                                           const float* __restrict__ HQ,
                                                           const float* __restrict__ rkt,
                                                           int C, int HO, int WO) {
    __shared__ __align__(16) float tile[64 * RSTRIDE];
    __shared__ int sbase[64];
    const int l = threadIdx.x & 63;
    const int w = threadIdx.x >> 6;
    const int o0 = blockIdx.x * 16;
    const int H = 2 * HO, W = 2 * WO;
    if (threadIdx.x < 64) {
        const int oi = threadIdx.x >> 2, p = threadIdx.x & 3;
        const int o = o0 + oi;
        const int wo = o % WO; int tmp = o / WO;
        const int ho = tmp % HO; tmp /= HO;
        const int c = tmp % C; const int b = tmp / C;
        sbase[threadIdx.x] = ((b * C + c) * H + 2 * ho + (p >> 1)) * W + 2 * wo + (p & 1);
    }
    __syncthreads();
    for (int i = threadIdx.x; i < 3200; i += 512) {
        const int slot = i / 50, q = i - slot * 50;
        const float4 v = *reinterpret_cast<const float4*>(in + (long)sbase[slot] * 200 + 4 * q);
        *reinterpret_cast<float4*>(&tile[slot * RSTRIDE + 4 * q]) = v;
    }
    __syncthreads();
    if (w == 0) {
        float rk[15];
        #pragma unroll
        for (int i = 0; i < 15; ++i) rk[i] = rkt[i];
        float p[15];
        #pragma unroll
        for (int i = 0; i < 15; ++i) p[i] = 0.0f;
        float* row = tile + l * RSTRIDE;
        for (int tq = 0; tq < 50; ++tq) {
            float4 xv = *reinterpret_cast<const float4*>(&row[4 * tq]);
            SCAN4(xv, p, rk)
            *reinterpret_cast<float4*>(&row[4 * tq]) = xv;
        }
    }
    __syncthreads();
    const int qb = l & ~3;
    const float* row = tile + l * RSTRIDE;
    const float4* HQ4 = reinterpret_cast<const float4*>(HQ);
    float* op = out + (long)(o0 + (l >> 2)) * 200;
    auto qsum = [&](float v) -> float {
        const float v0 = __shfl(v, qb + 0);
        const float v1 = __shfl(v, qb + 1);
        const float v2 = __shfl(v, qb + 2);
        const float v3 = __shfl(v, qb + 3);
        return (((v0 + v1) + v2) + v3) * 11.0f;
    };
    #pragma unroll
    for (int k = 0; k < 4; ++k) {
        const int id = FIR_ITEMS8[w][k];
        if (id < 0) break;
        const int t0 = 8 * id;
        const int jend = ((2 * id < 25) ? 2 * id : 25) + 1;
        float4 acc[2];
        acc[0] = make_float4(0.f, 0.f, 0.f, 0.f);
        acc[1] = make_float4(0.f, 0.f, 0.f, 0.f);
        fir_run2(row, HQ4, t0, jend, acc);
        #pragma unroll
        for (int d = 0; d < 2; ++d) {
            float4 r;
            r.x = qsum(acc[d].x); r.y = qsum(acc[d].y);
            r.z = qsum(acc[d].z); r.w = qsum(acc[d].w);
            if ((l & 3) == 0)
                *reinterpret_cast<float4*>(op + t0 + 4 * d) = r;
        }
    }
}

// ---------------------------------------------------------------------------
// conv1 (K=5): float4-of-t, transposed weights, 16 co accumulators.
// ---------------------------------------------------------------------------
template <int K, int PAD, int CI, int COG>
__global__ __launch_bounds__(256) void conv_kernel(const float* __restrict__ x,
                                                   const float* __restrict__ wt,
                                                   float* __restrict__ out,
                                                   int Co, int H, int W,
                                                   int HO, int WO) {
    const int l = threadIdx.x & 63;
    const int wv = threadIdx.x >> 6;
    if (l >= 50) return;
    const int p = blockIdx.x * 4 + wv;
    const int wo = p % WO, ho = p / WO;
    const int co0 = blockIdx.y * COG;
    const int b = blockIdx.z;
    const int t0 = l * 4;
    float4 acc[COG];
    #pragma unroll
    for (int c = 0; c < COG; ++c) acc[c] = make_float4(0.f, 0.f, 0.f, 0.f);
    const float* xb = x + ((long)b * CI * H * W) * 200 + t0;
    for (int ci = 0; ci < CI; ++ci) {
        #pragma unroll
        for (int kh = 0; kh < K; ++kh) {
            const int hi = ho + kh - PAD;
            if (hi < 0 || hi >= H) continue;
            #pragma unroll
            for (int kw = 0; kw < K; ++kw) {
                const int wi = wo + kw - PAD;
                if (wi < 0 || wi >= W) continue;
                const float4 v = *reinterpret_cast<const float4*>(
                    xb + ((long)(ci * H + hi) * W + wi) * 200);
                const float* wp = wt + ((ci * K + kh) * K + kw) * Co + co0;
                #pragma unroll
                for (int c = 0; c < COG; ++c) {
                    const float wv_ = wp[c];
                    acc[c].x = fmaf(wv_, v.x, acc[c].x);
                    acc[c].y = fmaf(wv_, v.y, acc[c].y);
                    acc[c].z = fmaf(wv_, v.z, acc[c].z);
                    acc[c].w = fmaf(wv_, v.w, acc[c].w);
                }
            }
        }
    }
    const long hwN = (long)HO * WO;
    const long ob = ((long)(b * Co + co0) * HO + ho) * WO + wo;
    #pragma unroll
    for (int c = 0; c < COG; ++c)
        *reinterpret_cast<float4*>(out + (ob + c * hwN) * 200 + t0) = acc[c];
}

// ---------------------------------------------------------------------------
// K=3 convs: ci-software-pipelined, zero-filled OOB taps (bit-exact).
// ---------------------------------------------------------------------------
template <int CI, int COG>
__global__ __launch_bounds__(256) void conv3_kernel(const float* __restrict__ x,
                                                    const float* __restrict__ wt,
                                                    float* __restrict__ out,
                                                    int Co, int H, int W) {
    const int l = threadIdx.x & 63;
    const int wv = threadIdx.x >> 6;
    if (l >= 50) return;
    const int p = blockIdx.x * 4 + wv;
    const int wo = p % W, ho = p / W;
    const int co0 = blockIdx.y * COG;
    const int b = blockIdx.z;
    const int t0 = l * 4;
    float4 acc[COG];
    #pragma unroll
    for (int c = 0; c < COG; ++c) acc[c] = make_float4(0.f, 0.f, 0.f, 0.f);

    bool vm[9];
    #pragma unroll
    for (int i = 0; i < 9; ++i) {
        const int hi = ho + i / 3 - 1, wi = wo + i % 3 - 1;
        vm[i] = (hi >= 0) && (hi < H) && (wi >= 0) && (wi < W);
    }
    const long cis = (long)H * W * 200;
    const float* pb = x + (long)b * CI * cis + ((long)(ho - 1) * W + (wo - 1)) * 200 + t0;

    float4 bufA[9], bufB[9];
    auto ld = [&](int ci, float4 (&B)[9]) {
        const float* pc = pb + ci * cis;
        #pragma unroll
        for (int i = 0; i < 9; ++i) {
            B[i] = vm[i] ? *reinterpret_cast<const float4*>(pc + ((i / 3) * W + (i % 3)) * 200)
                         : make_float4(0.f, 0.f, 0.f, 0.f);
        }
    };
    auto fm = [&](const float4 (&B)[9], int ci) {
        #pragma unroll
        for (int i = 0; i < 9; ++i) {
            const float* wp = wt + (ci * 9 + i) * Co + co0;
            #pragma unroll
            for (int c = 0; c < COG; ++c) {
                const float wv_ = wp[c];
                acc[c].x = fmaf(wv_, B[i].x, acc[c].x);
                acc[c].y = fmaf(wv_, B[i].y, acc[c].y);
                acc[c].z = fmaf(wv_, B[i].z, acc[c].z);
                acc[c].w = fmaf(wv_, B[i].w, acc[c].w);
            }
        }
    };

    ld(0, bufA);
    #pragma unroll 1
    for (int ci = 0; ci < CI; ci += 2) {
        ld(ci + 1, bufB);
        fm(bufA, ci);
        if (ci + 2 < CI) ld(ci + 2, bufA);
        fm(bufB, ci + 1);
    }

    const long hwN = (long)H * W;
    const long ob = ((long)(b * Co + co0) * H + ho) * W + wo;
    #pragma unroll
    for (int c = 0; c < COG; ++c)
        *reinterpret_cast<float4*>(out + (ob + c * hwN) * 200 + t0) = acc[c];
}

// ---------------------------------------------------------------------------
// Standalone spike scan (only the tiny final fc->spike uses this now).
// ---------------------------------------------------------------------------
__global__ __launch_bounds__(256) void spike_kernel(const float* __restrict__ v,
                                                    float* __restrict__ s,
                                                    const float* __restrict__ rkt,
                                                    int n) {
    const int nid = blockIdx.x * 256 + threadIdx.x;
    if (nid >= n) return;
    float rk[15];
    #pragma unroll
    for (int i = 0; i < 15; ++i) rk[i] = rkt[i];
    float p[15];
    #pragma unroll
    for (int i = 0; i < 15; ++i) p[i] = 0.0f;
    const float* vp = v + (long)nid * 200;
    float* sp = s + (long)nid * 200;
    for (int t = 0; t < 200; ++t) {
        const float u = vp[t] + p[0];
        const float sv = (u >= THETA) ? 1.0f : 0.0f;
        sp[t] = sv;
        #pragma unroll
        for (int i = 0; i < 14; ++i) p[i] = fmaf(sv, rk[i], p[i + 1]);
        p[14] = sv * rk[14];
    }
}

// ---------------------------------------------------------------------------
// FC: out[b,k,t] = sum_m x[b,m,t] * Wfc[k,m], m ascending (2304) — chain
// order unchanged (bit-exact).  LDS t-major xs[q][2308]; 256-thread stage
// (half the latency-exposed stage rounds of r10's 128), 80 compute lanes.
// ---------------------------------------------------------------------------
__global__ __launch_bounds__(256) void fc_kernel(const float* __restrict__ x,
                                                 const float* __restrict__ wf,
                                                 float* __restrict__ out) {
    __shared__ __align__(16) float xs[8 * 2308];
    const int b = blockIdx.x;          // 4
    const int t0 = blockIdx.y * 8;     // 25 chunks
    const int tid = threadIdx.x;
    const float* xb = x + (long)b * 2304 * 200 + t0;
    for (int i = tid; i < 4608; i += 256) {
        const int m = i >> 1, qh = (i & 1) * 4;
        const float4 v = *reinterpret_cast<const float4*>(xb + (long)m * 200 + qh);
        xs[(qh + 0) * 2308 + m] = v.x;
        xs[(qh + 1) * 2308 + m] = v.y;
        xs[(qh + 2) * 2308 + m] = v.z;
        xs[(qh + 3) * 2308 + m] = v.w;
    }
    __syncthreads();
    if (tid < 80) {
        const int k = tid >> 3, q = tid & 7;
        float a = 0.0f;
        const float* wp = wf + k * 2304;
        const float* xp = xs + q * 2308;
        for (int m4 = 0; m4 < 2304; m4 += 4) {
            const float4 xv = *reinterpret_cast<const float4*>(xp + m4);
            const float4 wv = *reinterpret_cast<const float4*>(wp + m4);
            a = fmaf(wv.x, xv.x, a);
            a = fmaf(wv.y, xv.y, a);
            a = fmaf(wv.z, xv.z, a);
            a = fmaf(wv.w, xv.w, a);
        }
        out[((long)b * 10 + k) * 200 + t0 + q] = a;
    }
}

extern "C" void kernel_launch(void* const* d_in, const int* in_sizes, int n_in,
                              void* d_out, int out_size, void* d_ws, size_t ws_size,
                              hipStream_t stream) {
    const float* x_in = (const float*)d_in[0];  // (4,2,50,50,200)
    const float* W1 = (const float*)d_in[1];    // (16,2,5,5)
    const float* W2 = (const float*)d_in[2];    // (32,16,3,3)
    const float* W3 = (const float*)d_in[3];    // (64,32,3,3)
    const float* W4 = (const float*)d_in[4];    // (64,64,3,3)
    const float* Wfc = (const float*)d_in[5];   // (10,64,6,6)
    float* outp = (float*)d_out;                // (4,10,200)

    float* ws = (float*)d_ws;
    float* HQ  = ws;                  // 144 (16B aligned)
    float* rk  = ws + 144;            // 15 (+1 pad)
    float* wt1 = ws + 160;            // 800
    float* wt2 = wt1 + 800;           // 4608
    float* wt3 = wt2 + 4608;          // 18432
    float* wt4 = wt3 + 18432;         // 36864
    float* A   = wt4 + 36864;         // 7,372,800
    float* B   = A + 7372800;         // 29,491,200
    float* C   = B + 29491200;        // 14,745,600

    hipLaunchKernelGGL(prep_kernel, dim3(238), dim3(256), 0, stream,
                       W1, W2, W3, W4, HQ, rk, wt1, wt2, wt3, wt4);

    // p0 = psp(input): 20000 series (no scan)
    hipLaunchKernelGGL((spikepsp_kernel<false>), dim3(313), dim3(512), 0, stream,
                       x_in, A, HQ, rk, 20000);
    // c1 = conv1(p0): (4,16,48,48,200)
    hipLaunchKernelGGL((conv_kernel<5, 1, 2, 16>), dim3(2304 / 4, 1, 4), dim3(256), 0, stream,
                       A, wt1, B, 16, 50, 50, 48, 48);
    // o1 = pool(psp(spike(c1))): 36864 outputs
    hipLaunchKernelGGL(spikepsppool_kernel, dim3(36864 / 16), dim3(512), 0, stream,
                       B, A, HQ, rk, 16, 24, 24);
    // p2 = psp(spike(o1)): 36864 series
    hipLaunchKernelGGL((spikepsp_kernel<true>), dim3(36864 / 64), dim3(512), 0, stream,
                       A, B, HQ, rk, 36864);
    // c2 = conv2(p2): (4,32,24,24,200)
    hipLaunchKernelGGL((conv3_kernel<16, 8>), dim3(576 / 4, 4, 4), dim3(256), 0, stream,
                       B, wt2, C, 32, 24, 24);
    // o2 = pool(psp(spike(c2))): 18432 outputs
    hipLaunchKernelGGL(spikepsppool_kernel, dim3(18432 / 16), dim3(512), 0, stream,
                       C, A, HQ, rk, 32, 12, 12);
    // p4 = psp(spike(o2)): 18432 series
    hipLaunchKernelGGL((spikepsp_kernel<true>), dim3(18432 / 64), dim3(512), 0, stream,
                       A, B, HQ, rk, 18432);
    // c3 = conv3(p4): (4,64,12,12,200)  [COG=8 — round-10 config]
    hipLaunchKernelGGL((conv3_kernel<32, 8>), dim3(144 / 4, 8, 4), dim3(256), 0, stream,
                       B, wt3, C, 64, 12, 12);
    // o3 = pool(psp(spike(c3))): 9216 outputs
    hipLaunchKernelGGL(spikepsppool_kernel, dim3(9216 / 16), dim3(512), 0, stream,
                       C, A, HQ, rk, 64, 6, 6);
    // p6 = psp(spike(o3)): 9216 series
    hipLaunchKernelGGL((spikepsp_kernel<true>), dim3(9216 / 64), dim3(512), 0, stream,
                       A, B, HQ, rk, 9216);
    // c4 = conv4(p6): (4,64,6,6,200)  [COG=4 — round-10 config]
    hipLaunchKernelGGL((conv3_kernel<64, 4>), dim3(36 / 4, 16, 4), dim3(256), 0, stream,
                       B, wt4, C, 64, 6, 6);
    // p7 = psp(spike(c4)): 9216 series
    hipLaunchKernelGGL((spikepsp_kernel<true>), dim3(9216 / 64), dim3(512), 0, stream,
                       C, B, HQ, rk, 9216);
    // fc: (4,10,200) — block per (b, 8-t chunk), 256 threads
    hipLaunchKernelGGL(fc_kernel, dim3(4, 25), dim3(256), 0, stream, B, Wfc, A);
    // final spike -> d_out: 40 series
    hipLaunchKernelGGL(spike_kernel, dim3(1), dim3(256), 0, stream, A, outp, rk, 40);
    (void)in_sizes; (void)n_in; (void)out_size; (void)ws_size;
}